// Round 1
// baseline (528.252 us; speedup 1.0000x reference)
//
#include <hip/hip_runtime.h>
#include <hip/hip_bf16.h>

#define NB 8
#define BIN 512
#define BOUT 512
#define BATCH 16384
#define NCOL (NB * BIN) /* 4096 */

typedef __bf16 bf16x8 __attribute__((ext_vector_type(8)));
typedef float floatx4 __attribute__((ext_vector_type(4)));

// async global->LDS, 16B per lane; LDS dest is wave-uniform base + lane*16
#define GLDS16(gptr, lptr)                                                 \
    __builtin_amdgcn_global_load_lds(                                      \
        (const __attribute__((address_space(1))) void*)(gptr),             \
        (__attribute__((address_space(3))) void*)(lptr), 16, 0, 0)

// ---------------------------------------------------------------------------
// Prep: W [g][o][i] fp32  ->  ws bf16, fragment-major 16B chunks:
//   chunk c = ((g*32 + n16)*16 + k32)*64 + lane
//   element j of chunk = W[g][n16*16 + (lane&15)][k32*32 + (lane>>4)*8 + j]
// GEMM B-staging is then a linear async copy and B ds_read_b128 lane-linear.
// ---------------------------------------------------------------------------
__global__ __launch_bounds__(256) void convW_kernel(const float* __restrict__ W,
                                                    __bf16* __restrict__ wsB) {
    int c = blockIdx.x * 256 + threadIdx.x;  // 0 .. 262143
    int lane = c & 63;
    int k32  = (c >> 6) & 15;
    int n16  = (c >> 10) & 31;
    int g    = c >> 15;
    int n = n16 * 16 + (lane & 15);
    int k = k32 * 32 + ((lane >> 4) << 3);
    const float* src = W + ((size_t)g * BOUT + n) * BIN + k;
    float4 f0 = *(const float4*)src;
    float4 f1 = *(const float4*)(src + 4);
    bf16x8 v;
    v[0] = (__bf16)f0.x; v[1] = (__bf16)f0.y; v[2] = (__bf16)f0.z; v[3] = (__bf16)f0.w;
    v[4] = (__bf16)f1.x; v[5] = (__bf16)f1.y; v[6] = (__bf16)f1.z; v[7] = (__bf16)f1.w;
    *(bf16x8*)(wsB + (size_t)c * 8) = v;
}

// ---------------------------------------------------------------------------
// GEMM v2: per block one 128x128 output tile of one group.
// BM=128, BN=128, BK=64; 256 threads = 4 waves; wave owns 32 ROWS x all 128
// cols (fi in {0,1} m-frags, j in 0..7 n-frags) -> A fragments are private
// per wave and loaded DIRECTLY from global (fp32 -> bf16 in reg, no A LDS):
// the MFMA A layout (row=lane&15, k=(lane>>4)*8+j) is a natural coalesced
// 16-row x 128B read of x.
// Pipeline: double-buffered B in LDS via global_load_lds, prefetch distance 1
// for BOTH B (GLDS) and A (regs); ONE __syncthreads per K-step whose vmcnt(0)
// drain lands on loads issued a full compute phase earlier.
// ---------------------------------------------------------------------------
__global__ __launch_bounds__(256, 3) void bgemm_kernel(
        const float* __restrict__ x, const __bf16* __restrict__ wsB,
        const float* __restrict__ bias, float* __restrict__ out) {
    __shared__ __align__(16) __bf16 Bsh[2][128 * 64];  // 2 x 16 KB

    // XCD swizzle: t = (b>>3) + 512*(b&7); each XCD owns one group g,
    // adjacent n-tiles share the x m-panel via L2. nwg=4096 % 8 == 0.
    int b = blockIdx.x;
    int t = (b >> 3) + ((b & 7) << 9);
    int g  = t >> 9;          // 0..7
    int mt = (t >> 2) & 127;  // 0..127
    int nt = t & 3;           // 0..3

    int tid  = threadIdx.x;
    int lane = tid & 63;
    int wave = tid >> 6;
    int m0 = mt * 128;

    // B staging addresses (linear in i): global chunk c = i*256 + tid
    unsigned bgoff0 = (unsigned)((((g * 32 + nt * 8 + (tid >> 7)) * 16) +
                                  ((tid >> 6) & 1)) * 64 + (tid & 63)) * 8;
    unsigned bldsoff0 = (unsigned)(wave * 64) * 8;  // wave-uniform LDS base (elems)

    // A fragment base: row = m0 + wave*32 + fi*16 + (lane&15),
    //                  k   = kb*64 + ks*32 + (lane>>4)*8 + j
    const float* xA = x + (size_t)(m0 + wave * 32 + (lane & 15)) * NCOL
                        + g * BIN + ((lane >> 4) << 3);

    floatx4 acc[2][8];
#pragma unroll
    for (int fi = 0; fi < 2; ++fi)
#pragma unroll
        for (int j = 0; j < 8; ++j) {
            floatx4 z = {0.f, 0.f, 0.f, 0.f};
            acc[fi][j] = z;
        }

    float4 Apre[2][8];  // [parity][fi*4 + ks*2 + half] -- const-indexed after unroll

    // Prologue: stage kb=0 (B -> Bsh[0], A -> Apre[0]); one exposed drain.
#pragma unroll
    for (int i = 0; i < 4; ++i)
        GLDS16(wsB + bgoff0 + i * 16384, &Bsh[0][bldsoff0 + i * 2048]);
#pragma unroll
    for (int fi = 0; fi < 2; ++fi)
#pragma unroll
        for (int ks = 0; ks < 2; ++ks) {
            const float* p = xA + (size_t)fi * 16 * NCOL + ks * 32;
            Apre[0][fi * 4 + ks * 2 + 0] = *(const float4*)p;
            Apre[0][fi * 4 + ks * 2 + 1] = *(const float4*)(p + 4);
        }
    __syncthreads();

#pragma unroll
    for (int kb = 0; kb < 8; ++kb) {
        const int cur = kb & 1;
        // --- prefetch kb+1 (issued first; waited only at end-of-iter barrier)
        if (kb < 7) {
#pragma unroll
            for (int i = 0; i < 4; ++i)
                GLDS16(wsB + bgoff0 + i * 16384 + (unsigned)(kb + 1) * 1024,
                       &Bsh[cur ^ 1][bldsoff0 + i * 2048]);
#pragma unroll
            for (int fi = 0; fi < 2; ++fi)
#pragma unroll
                for (int ks = 0; ks < 2; ++ks) {
                    const float* p = xA + (size_t)fi * 16 * NCOL + (kb + 1) * 64 + ks * 32;
                    Apre[cur ^ 1][fi * 4 + ks * 2 + 0] = *(const float4*)p;
                    Apre[cur ^ 1][fi * 4 + ks * 2 + 1] = *(const float4*)(p + 4);
                }
        }
        // --- convert current A (arrived before the previous barrier's drain)
        bf16x8 af[2][2];
#pragma unroll
        for (int fi = 0; fi < 2; ++fi)
#pragma unroll
            for (int ks = 0; ks < 2; ++ks) {
                float4 f0 = Apre[cur][fi * 4 + ks * 2 + 0];
                float4 f1 = Apre[cur][fi * 4 + ks * 2 + 1];
                bf16x8 v;
                v[0] = (__bf16)f0.x; v[1] = (__bf16)f0.y; v[2] = (__bf16)f0.z; v[3] = (__bf16)f0.w;
                v[4] = (__bf16)f1.x; v[5] = (__bf16)f1.y; v[6] = (__bf16)f1.z; v[7] = (__bf16)f1.w;
                af[fi][ks] = v;
            }
        // --- compute on buf[cur]: 16 ds_read_b128 + 32 MFMA per wave
#pragma unroll
        for (int j = 0; j < 8; ++j) {
            bf16x8 b0 = *(const bf16x8*)(&Bsh[cur][(unsigned)((j * 2 + 0) * 64 + lane) * 8]);
            bf16x8 b1 = *(const bf16x8*)(&Bsh[cur][(unsigned)((j * 2 + 1) * 64 + lane) * 8]);
#pragma unroll
            for (int fi = 0; fi < 2; ++fi) {
                acc[fi][j] = __builtin_amdgcn_mfma_f32_16x16x32_bf16(
                    af[fi][0], b0, acc[fi][j], 0, 0, 0);
                acc[fi][j] = __builtin_amdgcn_mfma_f32_16x16x32_bf16(
                    af[fi][1], b1, acc[fi][j], 0, 0, 0);
            }
        }
        // One barrier per K-step: drains this iter's prefetches (full phase of
        // cover) and orders buf reuse across waves.
        __syncthreads();
    }

    // Epilogue: C/D layout col = lane&15, row = (lane>>4)*4 + reg
    int coll = lane & 15;
    int rowq = (lane >> 4) * 4;
#pragma unroll
    for (int j = 0; j < 8; ++j) {
        int col = nt * 128 + j * 16 + coll;  // 0..511 within group
        float bv = bias[g * BOUT + col];
        size_t ocol = (size_t)g * BOUT + col;
#pragma unroll
        for (int fi = 0; fi < 2; ++fi) {
            int rbase = m0 + wave * 32 + fi * 16 + rowq;
#pragma unroll
            for (int r = 0; r < 4; ++r)
                out[(size_t)(rbase + r) * NCOL + ocol] = acc[fi][j][r] + bv;
        }
    }
}

extern "C" void kernel_launch(void* const* d_in, const int* in_sizes, int n_in,
                              void* d_out, int out_size, void* d_ws, size_t ws_size,
                              hipStream_t stream) {
    const float* x    = (const float*)d_in[0];
    const float* W    = (const float*)d_in[1];
    const float* bias = (const float*)d_in[2];
    float* out  = (float*)d_out;
    __bf16* wsB = (__bf16*)d_ws;  // 4 MB of scratch for bf16-swizzled W

    // W -> bf16 fragment-major swizzle (runs every call; ws is re-poisoned)
    convW_kernel<<<1024, 256, 0, stream>>>(W, wsB);
    // 8 groups x 128 m-tiles x 4 n-tiles = 4096 blocks
    bgemm_kernel<<<4096, 256, 0, stream>>>(x, wsB, bias, out);
}

// Round 2
// 498.617 us; speedup vs baseline: 1.0594x; 1.0594x over previous
//
#include <hip/hip_runtime.h>
#include <hip/hip_bf16.h>

#define NB 8
#define BIN 512
#define BOUT 512
#define BATCH 16384
#define NCOL (NB * BIN) /* 4096 */

typedef __bf16 bf16x8 __attribute__((ext_vector_type(8)));
typedef float floatx4 __attribute__((ext_vector_type(4)));

// async global->LDS, 16B per lane; LDS dest is wave-uniform base + lane*16
#define GLDS16(gptr, lptr)                                                 \
    __builtin_amdgcn_global_load_lds(                                      \
        (const __attribute__((address_space(1))) void*)(gptr),             \
        (__attribute__((address_space(3))) void*)(lptr), 16, 0, 0)

// ---------------------------------------------------------------------------
// Prep: W [g][o][i] fp32  ->  ws bf16, fragment-major 16B chunks:
//   chunk c = ((g*32 + n16)*16 + k32)*64 + lane
//   element j of chunk = W[g][n16*16 + (lane&15)][k32*32 + (lane>>4)*8 + j]
// GEMM B-staging is then a linear async copy and B ds_read_b128 lane-linear.
// ---------------------------------------------------------------------------
__global__ __launch_bounds__(256) void convW_kernel(const float* __restrict__ W,
                                                    __bf16* __restrict__ wsB) {
    int c = blockIdx.x * 256 + threadIdx.x;  // 0 .. 262143
    int lane = c & 63;
    int k32  = (c >> 6) & 15;
    int n16  = (c >> 10) & 31;
    int g    = c >> 15;
    int n = n16 * 16 + (lane & 15);
    int k = k32 * 32 + ((lane >> 4) << 3);
    const float* src = W + ((size_t)g * BOUT + n) * BIN + k;
    float4 f0 = *(const float4*)src;
    float4 f1 = *(const float4*)(src + 4);
    bf16x8 v;
    v[0] = (__bf16)f0.x; v[1] = (__bf16)f0.y; v[2] = (__bf16)f0.z; v[3] = (__bf16)f0.w;
    v[4] = (__bf16)f1.x; v[5] = (__bf16)f1.y; v[6] = (__bf16)f1.z; v[7] = (__bf16)f1.w;
    *(bf16x8*)(wsB + (size_t)c * 8) = v;
}

// ---------------------------------------------------------------------------
// GEMM v3 = v1 mapping + raw-barrier counted-vmcnt pipeline (T3/T4).
// BM=128, BN=128, BK=64; 256 threads = 4 waves; wave -> 64x64 (4x4 MFMA).
// LDS 48KB: Ash single-buffered (16KB, XOR-swizzled), Bsh double (2x16KB).
// Per iter kb:
//   convert A(kb) regs (loaded a full phase ago) -> ds_write Ash
//   issue GLDS B(kb+1) -> Bsh[cur^1]                (stays in flight!)
//   s_waitcnt lgkmcnt(0); s_barrier                 (raw: no vmcnt drain)
//   issue A(kb+1) global loads -> regs              (covered by MFMA phase)
//   16 ds_read + 32 MFMA on Ash / Bsh[cur]
//   s_waitcnt vmcnt(8); s_barrier                   (drains exactly the 4 GLDS,
//                                                    leaves the 8 A loads live)
// "memory"-clobbered waitcnt asms pin GLDS-before-A issue order so vmcnt(8)'s
// oldest-first drain provably covers the GLDS ops. sched_barrier(0) after each
// manual waitcnt (rule 18).
// ---------------------------------------------------------------------------
__global__ __launch_bounds__(256, 2) void bgemm_kernel(
        const float* __restrict__ x, const __bf16* __restrict__ wsB,
        const float* __restrict__ bias, float* __restrict__ out) {
    __shared__ __align__(16) __bf16 Ash[128 * 64];       // 16 KB
    __shared__ __align__(16) __bf16 Bsh[2][128 * 64];    // 32 KB

    // XCD swizzle: t = (b>>3) + 512*(b&7); each XCD owns one group g,
    // adjacent n-tiles reuse the x m-panel via L2. nwg=4096 % 8 == 0.
    int b = blockIdx.x;
    int t = (b >> 3) + ((b & 7) << 9);
    int g  = t >> 9;          // 0..7
    int mt = (t >> 2) & 127;  // 0..127
    int nt = t & 3;           // 0..3

    int tid  = threadIdx.x;
    int lane = tid & 63;
    int wave = tid >> 6;
    int wm = wave >> 1, wn = wave & 1;
    int m0 = mt * 128;

    // A staging precompute: thread loads 8 consecutive floats of one x row
    // (coalesced 32B/lane), converts, writes one swizzled 16B chunk.
    const float* axp[4];
    int achunk[4];
#pragma unroll
    for (int i = 0; i < 4; ++i) {
        int hr  = i * 256 + tid;
        int row = hr >> 3;  // 0..127
        int s   = hr & 7;   // 8-float chunk within BK=64
        axp[i]    = x + (size_t)(m0 + row) * NCOL + g * BIN + s * 8;
        achunk[i] = row * 8 + (s ^ (row & 7));  // XOR swizzle
    }
    // B staging precompute (linear async copy from pre-swizzled ws)
    unsigned bgoff[4];
    unsigned bldsoff[4];
#pragma unroll
    for (int i = 0; i < 4; ++i) {
        int c    = i * 256 + tid;
        int n16l = c >> 7;
        int k32l = (c >> 6) & 1;
        int lan  = c & 63;
        bgoff[i]   = (unsigned)((((g * 32 + nt * 8 + n16l) * 16) + k32l) * 64 + lan) * 8;
        bldsoff[i] = (unsigned)(i * 256 + wave * 64) * 8;  // wave-uniform
    }

    // A fragment read address components (swizzled)
    int a_m_lo = (lane & 15) * 8;   // (m&15)*8 chunks
    int a_quad = lane >> 4;         // k-quad
    int a_xor  = lane & 7;          // m&7 == lane&7

    floatx4 acc[4][4];
#pragma unroll
    for (int i = 0; i < 4; ++i)
#pragma unroll
        for (int j = 0; j < 4; ++j) {
            floatx4 z = {0.f, 0.f, 0.f, 0.f};
            acc[i][j] = z;
        }

    float4 Apre[4][2];  // one-parity A prefetch (32 VGPR)

    // ---- prologue: stage kb=0 (B -> Bsh[0] via GLDS, A -> regs), full drain
#pragma unroll
    for (int i = 0; i < 4; ++i)
        GLDS16(wsB + bgoff[i], &Bsh[0][bldsoff[i]]);
#pragma unroll
    for (int i = 0; i < 4; ++i) {
        Apre[i][0] = *(const float4*)(axp[i]);
        Apre[i][1] = *(const float4*)(axp[i] + 4);
    }
    asm volatile("s_waitcnt vmcnt(0)" ::: "memory");  // one-time full drain
    __builtin_amdgcn_sched_barrier(0);
    __builtin_amdgcn_s_barrier();

    for (int kb = 0; kb < 8; ++kb) {
        __bf16* bcur = Bsh[kb & 1];
        // --- convert A(kb) (regs arrived >= one full phase ago) + ds_write
#pragma unroll
        for (int i = 0; i < 4; ++i) {
            float4 f0 = Apre[i][0];
            float4 f1 = Apre[i][1];
            bf16x8 v;
            v[0] = (__bf16)f0.x; v[1] = (__bf16)f0.y; v[2] = (__bf16)f0.z; v[3] = (__bf16)f0.w;
            v[4] = (__bf16)f1.x; v[5] = (__bf16)f1.y; v[6] = (__bf16)f1.z; v[7] = (__bf16)f1.w;
            *(bf16x8*)(Ash + achunk[i] * 8) = v;
        }
        // --- issue B(kb+1) GLDS into the other buffer (in flight across barrier)
        if (kb < 7) {
#pragma unroll
            for (int i = 0; i < 4; ++i)
                GLDS16(wsB + bgoff[i] + (unsigned)(kb + 1) * 1024,
                       &Bsh[(kb & 1) ^ 1][bldsoff[i]]);
        }
        asm volatile("s_waitcnt lgkmcnt(0)" ::: "memory");  // ds_writes visible
        __builtin_amdgcn_sched_barrier(0);
        __builtin_amdgcn_s_barrier();                        // raw: no vmcnt drain
        __builtin_amdgcn_sched_barrier(0);
        // --- issue A(kb+1) loads now; MFMA phase below covers their latency
        if (kb < 7) {
#pragma unroll
            for (int i = 0; i < 4; ++i) {
                const float* p = axp[i] + (kb + 1) * 64;
                Apre[i][0] = *(const float4*)p;
                Apre[i][1] = *(const float4*)(p + 4);
            }
        }
        // --- compute on Ash / Bsh[cur]: 16 ds_read_b128 + 32 MFMA per wave
#pragma unroll
        for (int ks = 0; ks < 2; ++ks) {
            bf16x8 af[4], bfr[4];
#pragma unroll
            for (int i = 0; i < 4; ++i) {
                int chunk = ((wm * 4 + i) * 16) * 8 + a_m_lo +
                            ((ks * 4 + a_quad) ^ a_xor);
                af[i] = *(const bf16x8*)(Ash + chunk * 8);
            }
#pragma unroll
            for (int j = 0; j < 4; ++j)
                bfr[j] = *(const bf16x8*)(bcur + (((wn * 4 + j) * 2 + ks) * 64 + lane) * 8);
#pragma unroll
            for (int i = 0; i < 4; ++i)
#pragma unroll
                for (int j = 0; j < 4; ++j)
                    acc[i][j] = __builtin_amdgcn_mfma_f32_16x16x32_bf16(
                        af[i], bfr[j], acc[i][j], 0, 0, 0);
        }
        // --- end of iter: drain exactly the 4 GLDS (keep 8 A loads in flight)
        if (kb < 7) {
            asm volatile("s_waitcnt vmcnt(8)" ::: "memory");
            __builtin_amdgcn_sched_barrier(0);
            __builtin_amdgcn_s_barrier();
            __builtin_amdgcn_sched_barrier(0);
        }
    }

    // Epilogue: C/D layout col = lane&15, row = (lane>>4)*4 + reg
    int colbase = nt * 128 + wn * 64;
    int rowq = (lane >> 4) * 4;
    int coll = lane & 15;
#pragma unroll
    for (int j = 0; j < 4; ++j) {
        int col  = colbase + j * 16 + coll;  // 0..511 within group
        float bv = bias[g * BOUT + col];
        size_t ocol = (size_t)g * BOUT + col;
#pragma unroll
        for (int i = 0; i < 4; ++i) {
            int rbase = m0 + wm * 64 + i * 16 + rowq;
#pragma unroll
            for (int r = 0; r < 4; ++r)
                out[(size_t)(rbase + r) * NCOL + ocol] = acc[i][j][r] + bv;
        }
    }
}

extern "C" void kernel_launch(void* const* d_in, const int* in_sizes, int n_in,
                              void* d_out, int out_size, void* d_ws, size_t ws_size,
                              hipStream_t stream) {
    const float* x    = (const float*)d_in[0];
    const float* W    = (const float*)d_in[1];
    const float* bias = (const float*)d_in[2];
    float* out  = (float*)d_out;
    __bf16* wsB = (__bf16*)d_ws;  // 4 MB of scratch for bf16-swizzled W

    // W -> bf16 fragment-major swizzle (runs every call; ws is re-poisoned)
    convW_kernel<<<1024, 256, 0, stream>>>(W, wsB);
    // 8 groups x 128 m-tiles x 4 n-tiles = 4096 blocks
    bgemm_kernel<<<4096, 256, 0, stream>>>(x, wsB, bias, out);
}

// Round 3
// 482.589 us; speedup vs baseline: 1.0946x; 1.0332x over previous
//
#include <hip/hip_runtime.h>
#include <hip/hip_bf16.h>

#define NB 8
#define BIN 512
#define BOUT 512
#define BATCH 16384
#define NCOL (NB * BIN) /* 4096 */

typedef __bf16 bf16x8 __attribute__((ext_vector_type(8)));
typedef float floatx4 __attribute__((ext_vector_type(4)));

// ---------------------------------------------------------------------------
// Prep: W [g][o][i] fp32  ->  ws bf16, fragment-major 16B chunks:
//   chunk c = ((g*32 + n16)*16 + k32)*64 + lane
//   element j of chunk = W[g][n16*16 + (lane&15)][k32*32 + (lane>>4)*8 + j]
// A B-fragment is then a 1KB contiguous wave read straight from L2.
// ---------------------------------------------------------------------------
__global__ __launch_bounds__(256) void convW_kernel(const float* __restrict__ W,
                                                    __bf16* __restrict__ wsB) {
    int c = blockIdx.x * 256 + threadIdx.x;  // 0 .. 262143
    int lane = c & 63;
    int k32  = (c >> 6) & 15;
    int n16  = (c >> 10) & 31;
    int g    = c >> 15;
    int n = n16 * 16 + (lane & 15);
    int k = k32 * 32 + ((lane >> 4) << 3);
    const float* src = W + ((size_t)g * BOUT + n) * BIN + k;
    float4 f0 = *(const float4*)src;
    float4 f1 = *(const float4*)(src + 4);
    bf16x8 v;
    v[0] = (__bf16)f0.x; v[1] = (__bf16)f0.y; v[2] = (__bf16)f0.z; v[3] = (__bf16)f0.w;
    v[4] = (__bf16)f1.x; v[5] = (__bf16)f1.y; v[6] = (__bf16)f1.z; v[7] = (__bf16)f1.w;
    *(bf16x8*)(wsB + (size_t)c * 8) = v;
}

// ---------------------------------------------------------------------------
// GEMM v4: BM=64, BN=256, BK=64; 256 threads = 4 waves, each wave 64 rows x
// 64 cols (4 m-frags x 4 n-frags). All waves share the same 64 A rows.
//  - B: NO LDS. Fragment loads direct from ws (L2-resident, 512KB/group),
//    register double-buffer, prefetch distance 1.
//  - A: fp32 global -> reg (distance-2 prefetch) -> bf16 convert at END of
//    iter (2 compute phases + barrier of cover ~ HBM latency) -> 8KB
//    XOR-swizzled LDS buffer, double-buffered (16KB total).
//  - Sync: raw s_barrier + lgkmcnt(0) only. NO __syncthreads => no vmcnt(0)
//    drain; all global prefetches stay in flight across barriers and the
//    compiler inserts minimal counted vmcnt before first use.
//  - kb loop fully unrolled so all [kb&1] register indices are compile-time.
//  - out stored nontemporal (written once) to keep x resident in L3.
// ---------------------------------------------------------------------------
__global__ __launch_bounds__(256, 2) void bgemm_kernel(
        const float* __restrict__ x, const __bf16* __restrict__ wsB,
        const float* __restrict__ bias, float* __restrict__ out) {
    __shared__ __align__(16) __bf16 Ash[2][64 * 64];  // 2 x 8 KB

    // g = b&7 aligns group with XCD; within XCD, nt is innermost so the two
    // n-tiles of an x m-panel are dispatched adjacently (panel L2-hit).
    int b   = blockIdx.x;
    int g   = b & 7;
    int lcl = b >> 3;        // 0..511
    int mt  = lcl >> 1;      // 0..255
    int nt  = lcl & 1;       // 0..1
    int m0  = mt * 64;

    int tid  = threadIdx.x;
    int lane = tid & 63;
    int wave = tid >> 6;

    // A staging precompute: 2 chunks/thread; thread loads 8 consecutive
    // floats of one x row (32B, coalesced), writes one swizzled 16B chunk.
    const float* axp[2];
    int achunk[2];
#pragma unroll
    for (int i = 0; i < 2; ++i) {
        int h   = i * 256 + tid;
        int row = h >> 3;    // 0..63
        int s   = h & 7;     // 8-float chunk within BK=64
        axp[i]    = x + (size_t)(m0 + row) * NCOL + g * BIN + s * 8;
        achunk[i] = row * 8 + (s ^ (row & 7));  // XOR swizzle
    }

    // B fragment base: wave owns n16 = nt*16 + wave*4 + j, j=0..3.
    // elem offsets from base: j*8192, kb*1024, ks*512.
    const __bf16* bbase =
        wsB + ((size_t)((g * 32 + nt * 16 + wave * 4) * 16) * 64 + lane) * 8;

    floatx4 acc[4][4];
#pragma unroll
    for (int i = 0; i < 4; ++i)
#pragma unroll
        for (int j = 0; j < 4; ++j) {
            floatx4 z = {0.f, 0.f, 0.f, 0.f};
            acc[i][j] = z;
        }

    float4 Apre[2][2][2];  // [parity][chunk][half] -- static after unroll
    bf16x8 Bpre[2][4][2];  // [parity][j][ks]

    // ---- prologue: issue A(0), A(1), B(0); convert A(0) -> Ash[0]
#pragma unroll
    for (int i = 0; i < 2; ++i) {
        Apre[0][i][0] = *(const float4*)(axp[i]);
        Apre[0][i][1] = *(const float4*)(axp[i] + 4);
        Apre[1][i][0] = *(const float4*)(axp[i] + 64);
        Apre[1][i][1] = *(const float4*)(axp[i] + 68);
    }
#pragma unroll
    for (int j = 0; j < 4; ++j)
#pragma unroll
        for (int ks = 0; ks < 2; ++ks)
            Bpre[0][j][ks] = *(const bf16x8*)(bbase + j * 8192 + ks * 512);
#pragma unroll
    for (int i = 0; i < 2; ++i) {
        float4 f0 = Apre[0][i][0], f1 = Apre[0][i][1];
        bf16x8 v;
        v[0] = (__bf16)f0.x; v[1] = (__bf16)f0.y; v[2] = (__bf16)f0.z; v[3] = (__bf16)f0.w;
        v[4] = (__bf16)f1.x; v[5] = (__bf16)f1.y; v[6] = (__bf16)f1.z; v[7] = (__bf16)f1.w;
        *(bf16x8*)(&Ash[0][achunk[i] * 8]) = v;
    }
    asm volatile("s_waitcnt lgkmcnt(0)" ::: "memory");
    __builtin_amdgcn_sched_barrier(0);
    __builtin_amdgcn_s_barrier();
    __builtin_amdgcn_sched_barrier(0);

#pragma unroll
    for (int kb = 0; kb < 8; ++kb) {
        // --- issue A(kb+2) into the dead parity (consumed last iter)
        if (kb < 6) {
#pragma unroll
            for (int i = 0; i < 2; ++i) {
                const float* p = axp[i] + (kb + 2) * 64;
                Apre[kb & 1][i][0] = *(const float4*)p;
                Apre[kb & 1][i][1] = *(const float4*)(p + 4);
            }
        }
        // --- issue B(kb+1) fragment loads (L2-hot, ~1 phase of cover)
        if (kb < 7) {
#pragma unroll
            for (int j = 0; j < 4; ++j)
#pragma unroll
                for (int ks = 0; ks < 2; ++ks)
                    Bpre[(kb + 1) & 1][j][ks] = *(const bf16x8*)(
                        bbase + j * 8192 + (kb + 1) * 1024 + ks * 512);
        }
        __builtin_amdgcn_sched_barrier(0);  // pin prefetch issue before compute
        // --- compute(kb): 8 ds_read_b128 + 32 MFMA per wave
#pragma unroll
        for (int ks = 0; ks < 2; ++ks) {
            bf16x8 af[4];
#pragma unroll
            for (int fi = 0; fi < 4; ++fi) {
                int chunk = (fi * 16 + (lane & 15)) * 8 +
                            ((ks * 4 + (lane >> 4)) ^ (lane & 7));
                af[fi] = *(const bf16x8*)(&Ash[kb & 1][chunk * 8]);
            }
#pragma unroll
            for (int fi = 0; fi < 4; ++fi)
#pragma unroll
                for (int j = 0; j < 4; ++j)
                    acc[fi][j] = __builtin_amdgcn_mfma_f32_16x16x32_bf16(
                        af[fi], Bpre[kb & 1][j][ks], acc[fi][j], 0, 0, 0);
        }
        // --- convert A(kb+1) (issued 2 iters of cover ago) -> Ash[(kb+1)&1]
        if (kb < 7) {
#pragma unroll
            for (int i = 0; i < 2; ++i) {
                float4 f0 = Apre[(kb + 1) & 1][i][0];
                float4 f1 = Apre[(kb + 1) & 1][i][1];
                bf16x8 v;
                v[0] = (__bf16)f0.x; v[1] = (__bf16)f0.y; v[2] = (__bf16)f0.z; v[3] = (__bf16)f0.w;
                v[4] = (__bf16)f1.x; v[5] = (__bf16)f1.y; v[6] = (__bf16)f1.z; v[7] = (__bf16)f1.w;
                *(bf16x8*)(&Ash[(kb + 1) & 1][achunk[i] * 8]) = v;
            }
            asm volatile("s_waitcnt lgkmcnt(0)" ::: "memory");  // ds_writes visible
            __builtin_amdgcn_sched_barrier(0);
            __builtin_amdgcn_s_barrier();                        // raw: no vmcnt drain
            __builtin_amdgcn_sched_barrier(0);
        }
    }

    // Epilogue: C/D layout col = lane&15, row = (lane>>4)*4 + reg.
    // Nontemporal: out is write-once, keep x resident in L3.
    int coll = lane & 15;
    int rowq = (lane >> 4) * 4;
#pragma unroll
    for (int j = 0; j < 4; ++j) {
        int col  = nt * 256 + wave * 64 + j * 16 + coll;  // 0..511 within group
        float bv = bias[g * BOUT + col];
        size_t ocol = (size_t)g * BOUT + col;
#pragma unroll
        for (int fi = 0; fi < 4; ++fi) {
            int rbase = m0 + fi * 16 + rowq;
#pragma unroll
            for (int r = 0; r < 4; ++r)
                __builtin_nontemporal_store(
                    acc[fi][j][r] + bv,
                    &out[(size_t)(rbase + r) * NCOL + ocol]);
        }
    }
}

extern "C" void kernel_launch(void* const* d_in, const int* in_sizes, int n_in,
                              void* d_out, int out_size, void* d_ws, size_t ws_size,
                              hipStream_t stream) {
    const float* x    = (const float*)d_in[0];
    const float* W    = (const float*)d_in[1];
    const float* bias = (const float*)d_in[2];
    float* out  = (float*)d_out;
    __bf16* wsB = (__bf16*)d_ws;  // 4 MB of scratch for bf16-swizzled W

    // W -> bf16 fragment-major swizzle (runs every call; ws is re-poisoned)
    convW_kernel<<<1024, 256, 0, stream>>>(W, wsB);
    // 8 groups x 256 m-tiles x 2 n-tiles = 4096 blocks
    bgemm_kernel<<<4096, 256, 0, stream>>>(x, wsB, bias, out);
}